// Round 4
// baseline (3656.887 us; speedup 1.0000x reference)
//
#include <hip/hip_runtime.h>
#include <hip/hip_bf16.h>

// PrefixBLSTM: diagonal-batched bidirectional prefix LSTM + FC head.
// L=128 tokens, T=127 outputs, E=256, H=512, 4H=2048, V=32000.
// ALL float inputs are FLOAT32 (per reference setup_inputs); output is f32
// (threshold 2.060547e-3 == 0.02 * max|ref| -- the f32 relative path).
// MFMA runs on bf16 copies converted in a prep kernel (weights/emb) or
// in-register (fc_w, streamed f32).
//
// d_ws unused. All scratch lives in d_out (127*32000 f32 = 16,256,000 B):
//   [0,       131072)  hfO   : hf rows 0..127 bf16      (logits rows 0..2)
//   [131072,  262144)  hbO   : hb rows 0..127 bf16
//   [262144,  393216)  hS0   : backward-h double buf A  (zeroed)
//   [393216,  524288)  hS1   : backward-h double buf B  (zeroed)
//   [524288, 1572864)  gxF   : f32 128x2048
//   [1572864,2621440)  gxeB  : f32 128x2048
//   [2621440,2621696)  bar   : grid barrier   (zeroed)
//   [2621696,2623744)  hf0   : f32 fwd-h ping (zeroed)
//   [2623744,2625792)  hf1   : f32 fwd-h pong (zeroed)
//   [2625792,3674368)  WihF bf16 2048x256
//   [3674368,4722944)  WihB bf16 2048x256
//   [4722944,6820096)  WhhB bf16 2048x512
//   [6820096,6885632)  embT bf16 128x256 (gathered emb rows)
//   [16247808,16249856) c2  : staged row-126 [hf|hb]  == r126 cols 29952..30463
//   [16249856,16256000) hole: staged rows 0..2 [hf|hb]== r126 cols 30464..31999
//
// Stream-serialized phases:
//   memset -> prep -> gx_gemm -> lstm_diag (stages hole+c2)
//   -> fc_main   : rows 3..126, skip (r==126 && n>=29952); reads hfO/hbO
//   -> fc_small A: rows 0..2 all n (reads hole; clobbers hfO/hbO region)
//   -> fc_small B: row 126 n in [30464,32000) (reads c2; clobbers hole)
//   -> fc_small C: row 126 n in [29952,30464) (1 block; LDS-stages c2 first)

typedef __hip_bfloat16 bf;
typedef __attribute__((ext_vector_type(8))) short s8b;   // 8 bf16 (MFMA A/B frag)
typedef __attribute__((ext_vector_type(4))) short s4b;   // 4 bf16
typedef __attribute__((ext_vector_type(4))) float f4;    // MFMA C/D frag

#define MFMA16(a, b, c) __builtin_amdgcn_mfma_f32_16x16x32_bf16((a), (b), (c), 0, 0, 0)
#define GRID_LSTM 32

__device__ __forceinline__ float sigm(float x) { return 1.f / (1.f + __expf(-x)); }
__device__ __forceinline__ float tanh_(float x) { return 1.f - 2.f / (__expf(2.f * x) + 1.f); }

__device__ __forceinline__ short f2bs(float f) {   // f32 -> bf16 bits (RNE)
  bf h = __float2bfloat16(f);
  short s;
  __builtin_memcpy(&s, &h, 2);
  return s;
}
__device__ __forceinline__ s8b cvt8(const float* __restrict__ p) {
  float4 v0 = *(const float4*)p;
  float4 v1 = *(const float4*)(p + 4);
  s8b r;
  r[0] = f2bs(v0.x); r[1] = f2bs(v0.y); r[2] = f2bs(v0.z); r[3] = f2bs(v0.w);
  r[4] = f2bs(v1.x); r[5] = f2bs(v1.y); r[6] = f2bs(v1.z); r[7] = f2bs(v1.w);
  return r;
}
__device__ __forceinline__ s4b cvt4(float4 v) {
  s4b r;
  r[0] = f2bs(v.x); r[1] = f2bs(v.y); r[2] = f2bs(v.z); r[3] = f2bs(v.w);
  return r;
}

// ---------------------------------------------------------------------------
// Kernel 0: prep — f32->bf16 conversions + embedding gather.
// ---------------------------------------------------------------------------
__global__ __launch_bounds__(256) void prep(
    const float* __restrict__ Wihf, const float* __restrict__ Wihb,
    const float* __restrict__ Whhb, const float* __restrict__ emb,
    const int* __restrict__ x,
    short* __restrict__ wihfB, short* __restrict__ wihbB,
    short* __restrict__ whhbB, short* __restrict__ embT)
{
  const int gid = blockIdx.x * 256 + threadIdx.x;
  const int stride = gridDim.x * 256;
  for (int i = gid; i < 131072; i += stride)       // 2048*256 / 4
    ((s4b*)wihfB)[i] = cvt4(((const float4*)Wihf)[i]);
  for (int i = gid; i < 131072; i += stride)
    ((s4b*)wihbB)[i] = cvt4(((const float4*)Wihb)[i]);
  for (int i = gid; i < 262144; i += stride)       // 2048*512 / 4
    ((s4b*)whhbB)[i] = cvt4(((const float4*)Whhb)[i]);
  for (int i = gid; i < 8192; i += stride) {       // 128*256 / 4
    const int t = i >> 6, k = (i & 63) << 2;
    ((s4b*)embT)[i] = cvt4(*(const float4*)(emb + x[t] * 256 + k));
  }
}

// ---------------------------------------------------------------------------
// Kernel 1: gx precompute (both directions). 128x2048, K=256 GEMM each.
// A = embT bf16 (gathered), B = Wih bf16, bias = b_ih+b_hh (f32).
// ---------------------------------------------------------------------------
__global__ __launch_bounds__(256) void gx_gemm(
    const short* __restrict__ embT,
    const short* __restrict__ WfB, const short* __restrict__ WbB,
    const float* __restrict__ bif, const float* __restrict__ bhf,
    const float* __restrict__ bib, const float* __restrict__ bhb,
    float* __restrict__ gxF, float* __restrict__ gxeB)
{
  const int tid  = threadIdx.x;
  const int nb   = blockIdx.x & 15;
  const int mat  = blockIdx.x >> 4;
  const short* W = mat ? WbB : WfB;
  const float* bi = mat ? bib : bif;
  const float* bh = mat ? bhb : bhf;
  float* out     = mat ? gxeB : gxF;

  const int wv = tid >> 6, lane = tid & 63, quad = lane >> 4, l16 = lane & 15;
  const int wm = wv >> 1, wn = wv & 1;
  const int m0 = wm * 64;
  const int n0 = nb * 128 + wn * 64;

  f4 acc[4][4];
  #pragma unroll
  for (int i = 0; i < 4; ++i)
    #pragma unroll
    for (int j = 0; j < 4; ++j) { acc[i][j][0]=0.f; acc[i][j][1]=0.f; acc[i][j][2]=0.f; acc[i][j][3]=0.f; }

  #pragma unroll
  for (int kt = 0; kt < 8; ++kt) {
    const int k = kt * 32 + quad * 8;
    s8b a[4], bb[4];
    #pragma unroll
    for (int mt = 0; mt < 4; ++mt) a[mt]  = *(const s8b*)(embT + (m0 + mt * 16 + l16) * 256 + k);
    #pragma unroll
    for (int nt = 0; nt < 4; ++nt) bb[nt] = *(const s8b*)(W + (n0 + nt * 16 + l16) * 256 + k);
    #pragma unroll
    for (int mt = 0; mt < 4; ++mt)
      #pragma unroll
      for (int nt = 0; nt < 4; ++nt)
        acc[mt][nt] = MFMA16(a[mt], bb[nt], acc[mt][nt]);
  }

  #pragma unroll
  for (int nt = 0; nt < 4; ++nt) {
    const int n = n0 + nt * 16 + l16;
    const float bias = bi[n] + bh[n];
    #pragma unroll
    for (int mt = 0; mt < 4; ++mt)
      #pragma unroll
      for (int r = 0; r < 4; ++r) {
        const int m = m0 + mt * 16 + quad * 4 + r;
        out[m * 2048 + n] = acc[mt][nt][r] + bias;
      }
  }
}

// ---------------------------------------------------------------------------
// Kernel 2: persistent diagonal LSTM (32 blocks x 256). Block b owns hidden
// units [16b,16b+16) for both directions. One device barrier per step.
// ---------------------------------------------------------------------------
__global__ __launch_bounds__(256) void lstm_diag(
    const float* __restrict__ WhhF, const short* __restrict__ WhhB,
    const float* __restrict__ gxF, const float* __restrict__ gxeB,
    bf* __restrict__ hS0, bf* __restrict__ hS1,
    float* __restrict__ hf0, float* __restrict__ hf1,
    bf* __restrict__ hfOut, bf* __restrict__ hbOut,
    bf* __restrict__ hole, bf* __restrict__ c2,
    int* __restrict__ bar)
{
  const int tid  = threadIdx.x;
  const int blk  = blockIdx.x;
  const int u0   = blk << 4;
  const int wv   = tid >> 6;
  const int lane = tid & 63;
  const int quad = lane >> 4;
  const int l16  = lane & 15;

  __shared__ float gatesF[64];
  __shared__ float cFs[16];
  if (tid < 16) cFs[tid] = 0.f;
  __syncthreads();

  float cB[8];
  #pragma unroll
  for (int i = 0; i < 8; ++i) cB[i] = 0.f;

  const int frow  = tid >> 2;           // 0..63: gate-chunk*16 + u-offset
  const int fgate = frow >> 4;
  const int fu    = frow & 15;
  const int fk0   = (tid & 3) << 7;
  const float* wfRow = WhhF + ((fgate << 9) + u0 + fu) * 512 + fk0;

  for (int s = 0; s < 127; ++s) {
    const bf* hRd     = (s & 1) ? hS0 : hS1;
    bf*       hWr     = (s & 1) ? hS1 : hS0;
    const float* hfRd = (s & 1) ? hf0 : hf1;
    float*       hfWr = (s & 1) ? hf1 : hf0;

    // ---- backward batched GEMM + gates (this wave's 2 M-tiles) ----
    #pragma unroll
    for (int half = 0; half < 2; ++half) {
      const int mbase = ((wv << 1) + half) << 4;
      if (mbase + 15 >= s) {
        f4 acc0, acc1, acc2, acc3;
        acc0[0]=acc0[1]=acc0[2]=acc0[3]=0.f;
        acc1[0]=acc1[1]=acc1[2]=acc1[3]=0.f;
        acc2[0]=acc2[1]=acc2[2]=acc2[3]=0.f;
        acc3[0]=acc3[1]=acc3[2]=acc3[3]=0.f;
        const bf*    aPtr = hRd + ((mbase + l16) << 9) + (quad << 3);
        const short* bPtr = WhhB + ((u0 + l16) << 9) + (quad << 3);
        #pragma unroll
        for (int kt = 0; kt < 16; ++kt) {
          const int ko = kt << 5;
          s8b af = *(const s8b*)(aPtr + ko);
          s8b b0 = *(const s8b*)(bPtr + ko);
          s8b b1 = *(const s8b*)(bPtr + (1 << 18) + ko);
          s8b b2 = *(const s8b*)(bPtr + (2 << 18) + ko);
          s8b b3 = *(const s8b*)(bPtr + (3 << 18) + ko);
          acc0 = MFMA16(af, b0, acc0);
          acc1 = MFMA16(af, b1, acc1);
          acc2 = MFMA16(af, b2, acc2);
          acc3 = MFMA16(af, b3, acc3);
        }
        #pragma unroll
        for (int r = 0; r < 4; ++r) {
          const int m = mbase + (quad << 2) + r;
          if (m >= s && m <= 126) {
            const int j = m - s;                       // token consumed
            const float* gx = gxeB + j * 2048 + u0 + l16;
            const float gi = acc0[r] + gx[0];
            const float gf = acc1[r] + gx[512];
            const float gg = acc2[r] + gx[1024];
            const float go = acc3[r] + gx[1536];
            const float ii = sigm(gi), ff = sigm(gf);
            const float g2 = tanh_(gg), oo = sigm(go);
            const float cn = ff * cB[half * 4 + r] + ii * g2;
            cB[half * 4 + r] = cn;
            const bf hn = __float2bfloat16(oo * tanh_(cn));
            const int idx = (m << 9) + u0 + l16;
            if (m > s) hWr[idx] = hn;
            else       hbOut[idx] = hn;                // m == s: finalized
          }
        }
      }
    }

    // ---- forward LSTM (token s): f32 matvec, 4 threads per gate row ----
    {
      const float* hv = hfRd + fk0;
      float a0 = 0.f;
      #pragma unroll
      for (int k = 0; k < 128; k += 8) {
        float4 w0 = *(const float4*)(wfRow + k);
        float4 w1 = *(const float4*)(wfRow + k + 4);
        float4 h0 = *(const float4*)(hv + k);
        float4 h1 = *(const float4*)(hv + k + 4);
        a0 += w0.x*h0.x + w0.y*h0.y + w0.z*h0.z + w0.w*h0.w
            + w1.x*h1.x + w1.y*h1.y + w1.z*h1.z + w1.w*h1.w;
      }
      a0 += __shfl_xor(a0, 1);
      a0 += __shfl_xor(a0, 2);
      if ((tid & 3) == 0)
        gatesF[frow] = a0 + gxF[s * 2048 + (fgate << 9) + u0 + fu];
    }
    __syncthreads();
    if (tid < 16) {
      const float gi = gatesF[tid], gf = gatesF[16 + tid];
      const float gg = gatesF[32 + tid], go = gatesF[48 + tid];
      const float ii = sigm(gi), ff = sigm(gf), g2 = tanh_(gg), oo = sigm(go);
      const float cn = ff * cFs[tid] + ii * g2;
      cFs[tid] = cn;
      const float hn = oo * tanh_(cn);
      hfWr[u0 + tid] = hn;
      hfOut[(s << 9) + u0 + tid] = __float2bfloat16(hn);
    }

    // ---- grid barrier (monotone counter, agent scope) ----
    __syncthreads();
    if (tid == 0) {
      __threadfence();
      __hip_atomic_fetch_add(bar, 1, __ATOMIC_RELEASE, __HIP_MEMORY_SCOPE_AGENT);
      const int target = (s + 1) * GRID_LSTM;
      while (__hip_atomic_load(bar, __ATOMIC_ACQUIRE, __HIP_MEMORY_SCOPE_AGENT) < target) {
        __builtin_amdgcn_s_sleep(1);
      }
    }
    __syncthreads();
  }

  // ---- stage relay data (all writes barrier-visible) ----
  if (blk == 0) {   // hole: rows 0..2, per-row [hf(512)|hb(512)]
    for (int i = tid; i < 3 * 1024; i += 256) {
      const int r = i >> 10, k = i & 1023;
      hole[i] = (k < 512) ? hfOut[r * 512 + k] : hbOut[r * 512 + (k - 512)];
    }
  }
  if (blk == 1) {   // c2: row 126 [hf(512)|hb(512)]
    for (int i = tid; i < 1024; i += 256)
      c2[i] = (i < 512) ? hfOut[126 * 512 + i] : hbOut[126 * 512 + (i - 512)];
  }
}

// ---------------------------------------------------------------------------
// Kernel 3: FC main. Rows 3..126 (skip r126 n>=29952). A = hfO/hbO bf16;
// B = fc_w f32 streamed once, converted in-register. Output f32.
// ---------------------------------------------------------------------------
__global__ __launch_bounds__(256) void fc_main(
    const bf* __restrict__ hfOut, const bf* __restrict__ hbOut,
    const float* __restrict__ fcw, const float* __restrict__ fcb,
    float* __restrict__ out)
{
  const int tid = threadIdx.x;
  const int wv = tid >> 6, lane = tid & 63, quad = lane >> 4, l16 = lane & 15;
  const int wm = wv >> 1, wn = wv & 1;
  const int m0 = wm * 64;
  const int n0 = blockIdx.x * 128 + wn * 64;

  f4 acc[4][4];
  #pragma unroll
  for (int i = 0; i < 4; ++i)
    #pragma unroll
    for (int j = 0; j < 4; ++j) { acc[i][j][0]=0.f; acc[i][j][1]=0.f; acc[i][j][2]=0.f; acc[i][j][3]=0.f; }

  #pragma unroll
  for (int half = 0; half < 2; ++half) {
    const bf* A = half ? hbOut : hfOut;
    #pragma unroll
    for (int kt = 0; kt < 16; ++kt) {
      const int k = kt * 32 + quad * 8;
      s8b a[4], b[4];
      #pragma unroll
      for (int mt = 0; mt < 4; ++mt) a[mt] = *(const s8b*)(A + (m0 + mt * 16 + l16) * 512 + k);
      #pragma unroll
      for (int nt = 0; nt < 4; ++nt) b[nt] = cvt8(fcw + (n0 + nt * 16 + l16) * 1024 + half * 512 + k);
      #pragma unroll
      for (int mt = 0; mt < 4; ++mt)
        #pragma unroll
        for (int nt = 0; nt < 4; ++nt)
          acc[mt][nt] = MFMA16(a[mt], b[nt], acc[mt][nt]);
    }
  }

  #pragma unroll
  for (int nt = 0; nt < 4; ++nt) {
    const int n = n0 + nt * 16 + l16;
    const float bb = fcb[n];
    #pragma unroll
    for (int mt = 0; mt < 4; ++mt)
      #pragma unroll
      for (int r = 0; r < 4; ++r) {
        const int m = m0 + mt * 16 + quad * 4 + r;
        if (m >= 3 && m < 127 && !(m == 126 && n >= 29952))
          out[m * 32000 + n] = acc[mt][nt][r] + bb;
      }
  }
}

// ---------------------------------------------------------------------------
// Kernel 4: FC relay. rowCount (<=3) rows from rowBase, cols [nstart,nstart+
// ncols), A rows ([hf|hb], 1024 each) staged from `stage` into LDS before any
// write (so a 1-block launch may overwrite its own stage region).
// ---------------------------------------------------------------------------
__global__ __launch_bounds__(256) void fc_small(
    const bf* __restrict__ stage,
    const float* __restrict__ fcw, const float* __restrict__ fcb,
    float* __restrict__ out,
    int nstart, int ncols, int rowBase, int rowCount)
{
  __shared__ short As[16 * 1032];
  const int tid = threadIdx.x;
  for (int i = tid; i < 16 * 1032; i += 256) As[i] = 0;
  __syncthreads();
  for (int i = tid; i < rowCount * 1024; i += 256) {
    const int r = i >> 10, k = i & 1023;
    As[r * 1032 + k] = ((const short*)stage)[i];
  }
  __syncthreads();

  const int wv = tid >> 6, lane = tid & 63, quad = lane >> 4, l16 = lane & 15;
  const int nEnd = nstart + ncols;
  const int waveN = nstart + blockIdx.x * 1024 + wv * 256;

  for (int t4 = 0; t4 < 4; ++t4) {
    const int n0 = waveN + t4 * 64;
    if (n0 >= nEnd) break;
    f4 acc[4];
    #pragma unroll
    for (int nt = 0; nt < 4; ++nt) { acc[nt][0]=0.f; acc[nt][1]=0.f; acc[nt][2]=0.f; acc[nt][3]=0.f; }
    #pragma unroll
    for (int kt = 0; kt < 32; ++kt) {
      const int k = kt * 32 + quad * 8;
      s8b a = *(const s8b*)(As + l16 * 1032 + k);
      s8b b[4];
      #pragma unroll
      for (int nt = 0; nt < 4; ++nt) b[nt] = cvt8(fcw + (n0 + nt * 16 + l16) * 1024 + k);
      #pragma unroll
      for (int nt = 0; nt < 4; ++nt) acc[nt] = MFMA16(a, b[nt], acc[nt]);
    }
    #pragma unroll
    for (int nt = 0; nt < 4; ++nt) {
      const int n = n0 + nt * 16 + l16;
      const float bb = fcb[n];
      #pragma unroll
      for (int r = 0; r < 4; ++r) {
        const int m = quad * 4 + r;
        if (m < rowCount)
          out[(rowBase + m) * 32000 + n] = acc[nt][r] + bb;
      }
    }
  }
}

// ---------------------------------------------------------------------------
extern "C" void kernel_launch(void* const* d_in, const int* in_sizes, int n_in,
                              void* d_out, int out_size, void* d_ws, size_t ws_size,
                              hipStream_t stream) {
  const int*   x    = (const int*)d_in[0];
  const float* emb  = (const float*)d_in[1];
  const float* Wihf = (const float*)d_in[2];
  const float* Whhf = (const float*)d_in[3];
  const float* bihf = (const float*)d_in[4];
  const float* bhhf = (const float*)d_in[5];
  const float* Wihb = (const float*)d_in[6];
  const float* Whhb = (const float*)d_in[7];
  const float* bihb = (const float*)d_in[8];
  const float* bhhb = (const float*)d_in[9];
  const float* fcw  = (const float*)d_in[10];
  const float* fcb  = (const float*)d_in[11];
  float* out = (float*)d_out;

  char* S = (char*)d_out;                 // ALL scratch lives in d_out
  bf*    hfO   = (bf*)(S + 0);
  bf*    hbO   = (bf*)(S + 131072);
  bf*    hS0   = (bf*)(S + 262144);
  bf*    hS1   = (bf*)(S + 393216);
  float* gxF   = (float*)(S + 524288);
  float* gxeB  = (float*)(S + 1572864);
  int*   bar   = (int*)(S + 2621440);
  float* hf0   = (float*)(S + 2621696);
  float* hf1   = (float*)(S + 2623744);
  short* wihfB = (short*)(S + 2625792);
  short* wihbB = (short*)(S + 3674368);
  short* whhbB = (short*)(S + 4722944);
  short* embT  = (short*)(S + 6820096);
  bf*    c2    = (bf*)(S + 16247808);     // r126 cols 29952..30463
  bf*    hole  = (bf*)(S + 16249856);     // r126 cols 30464..31999

  // zero hS0/hS1 + (gx harmlessly) + bar + hf0/hf1
  hipMemsetAsync(S + 262144, 0, 2625792 - 262144, stream);

  hipLaunchKernelGGL(prep, dim3(256), dim3(256), 0, stream,
                     Wihf, Wihb, Whhb, emb, x, wihfB, wihbB, whhbB, embT);
  hipLaunchKernelGGL(gx_gemm, dim3(32), dim3(256), 0, stream,
                     embT, wihfB, wihbB, bihf, bhhf, bihb, bhhb, gxF, gxeB);
  hipLaunchKernelGGL(lstm_diag, dim3(GRID_LSTM), dim3(256), 0, stream,
                     Whhf, whhbB, gxF, gxeB, hS0, hS1, hf0, hf1, hfO, hbO, hole, c2, bar);
  hipLaunchKernelGGL(fc_main, dim3(250), dim3(256), 0, stream,
                     hfO, hbO, fcw, fcb, out);
  // rows 0..2 (reads hole; clobbers hfO/hbO with final logits)
  hipLaunchKernelGGL(fc_small, dim3(32), dim3(256), 0, stream,
                     hole, fcw, fcb, out, 0, 32000, 0, 3);
  // row 126 cols 30464..31999 (reads c2; clobbers hole)
  hipLaunchKernelGGL(fc_small, dim3(2), dim3(256), 0, stream,
                     c2, fcw, fcb, out, 30464, 1536, 126, 1);
  // row 126 cols 29952..30463 (1 block; LDS-stages c2 then overwrites it)
  hipLaunchKernelGGL(fc_small, dim3(1), dim3(256), 0, stream,
                     c2, fcw, fcb, out, 29952, 512, 126, 1);
}